// Round 12
// baseline (506.742 us; speedup 1.0000x reference)
//
#include <hip/hip_runtime.h>
#include <hip/hip_bf16.h>
#include <math.h>

// TemporalSkeletonBranch — Round 21: W73 with FORCED __launch_bounds__(512,8).
// R20 post-mortem: declaration-only hb shrink lost the regalloc lottery
// AGAIN (sibling W=56 VGPR, W73 drifted >64; gate fell back; 305/505us).
// R21 insight: R10's forced-bounds disaster was natural-140-forced-128
// (allocator overshoot -> spills). Here natural pressure is 56, budget 64
// (launch_bounds(512,8): 8 waves/EU x 512-VGPR pool / 8 = 64) — 8 regs of
// slack, trivially satisfiable. The directive prevents DRIFT, not squeeze.
// Gate (numRegs<=64 && no scratch) still protects; fallback = proven W.
// W73: hb[73*HSTR] -> LDS 40,352 <= 40,960 -> 4 blocks x 8 waves = 32
// waves/CU (vs W's 24). Correctness: R12-validated row-aliasing (hb rows
// 66-79 reads feed discarded outputs; max offset 21,712B < block size).

#define NJ 33
#define NF 52
#define NH 128
#define NT 256
#define NB 64
#define NSAMP (NB*NT)       // 16384
#define SPB 2               // samples per block
#define NBLKS (NSAMP/SPB)   // 8192
#define HSTR 136            // hb row stride (halves)
#define PSTR 40             // Pt k-stride (halves)

typedef unsigned short u16;
typedef _Float16 f16;
typedef f16   half8 __attribute__((ext_vector_type(8)));
typedef f16   h2    __attribute__((ext_vector_type(2)));
typedef float f32x4 __attribute__((ext_vector_type(4)));

// ---- workspace layout ----
#define HO_W0    0            // [n=128][k=64]
#define HO_S0    8192
#define HO_W1    16384        // [n=128][k=128]
#define HO_W2    32768
#define HO_TW1   49152
#define HO_ADJ32 65536        // [32][32] f16, rows/cols 25..31 = 0
#define H_TOTAL  66560
#define FO_BASE  (H_TOTAL/2)  // 33280 floats
#define FO_A0    (FO_BASE+0)  // [L*256 + {A:c, D:128+c}]
#define FO_SB0   (FO_BASE+768)
#define FO_TB1   (FO_BASE+896)
#define FO_TW2   (FO_BASE+1024)
#define FO_FLG   (FO_BASE+1152)   // int: x is bf16?
#define FO_XT    (FO_BASE+1280)
#define FO_SC    (FO_XT + NSAMP*NH)

__device__ __forceinline__ float bf2f(u16 u) { return __uint_as_float(((unsigned)u) << 16); }
__device__ __forceinline__ float ldv(const void* p, long i, int f) {
    float r;
    if (f) r = bf2f(((const u16*)p)[i]);
    else   r = ((const float*)p)[i];
    return r;
}
__device__ int detect_bf16(const void* p) {
    const u16* q = (const u16*)p;
    int nz = 0, ok = 0;
#pragma unroll
    for (int k = 0; k < 64; k++) {
        u16 u = q[k];
        if (u & 0x7FFF) {
            nz++;
            int e = (u >> 7) & 0xFF;
            ok += (e >= 0x40 && e <= 0xBF) ? 1 : 0;
        }
    }
    return (nz == 0) || (ok * 20 >= nz * 19);
}

// clamped tanh-form gelu (R9-proven): exp2+rcp
__device__ __forceinline__ float gelu_c(float x) {
    float xc = fminf(fmaxf(x, -8.f), 8.f);
    float u  = xc * fmaf(xc * xc, 0.10294324f, 2.3022082f);
#if __has_builtin(__builtin_amdgcn_exp2f)
    float e  = __builtin_amdgcn_exp2f(u);
#else
    float e  = exp2f(u);
#endif
#if __has_builtin(__builtin_amdgcn_rcpf)
    float tt = (e - 1.f) * __builtin_amdgcn_rcpf(e + 1.f);
#else
    float tt = (e - 1.f) / (e + 1.f);
#endif
    float hx = 0.5f * x;
    return fmaf(hx, tt, hx);
}

#define MFMA16(a, b, c) __builtin_amdgcn_mfma_f32_16x16x32_f16(a, b, c, 0, 0, 0)

// ---- prep: 65-block tiled transpose + folded BN + adj32 + dtype flags ----
__global__ __launch_bounds__(256) void prep(
    const void* x, const void* adj,
    const void* W0, const void* b0, const void* S0, const void* sb0,
    const void* g0, const void* be0, const void* m0, const void* v0,
    const void* W1, const void* b1, const void* g1, const void* be1, const void* m1, const void* v1,
    const void* W2, const void* b2, const void* g2, const void* be2, const void* m2, const void* v2,
    const void* tW1, const void* tb1, const void* tW2,
    void* ws)
{
    f16* H = (f16*)ws; float* F = (float*)ws;
    const int bi = blockIdx.x, t = threadIdx.x;

    if (bi < 64) {
        const void* src; int dst, kt, nt, Kvalid, Kd;
        if (bi < 16)      { src = W1;  dst = HO_W1;  kt = (bi>>2)&3;    nt = bi&3;      Kvalid = 128; Kd = 128; }
        else if (bi < 32) { src = W2;  dst = HO_W2;  kt = ((bi-16)>>2); nt = (bi-16)&3; Kvalid = 128; Kd = 128; }
        else if (bi < 48) { src = tW1; dst = HO_TW1; kt = ((bi-32)>>2); nt = (bi-32)&3; Kvalid = 128; Kd = 128; }
        else if (bi < 56) { src = W0;  dst = HO_W0;  kt = ((bi-48)>>2); nt = (bi-48)&3; Kvalid = NF;  Kd = 64;  }
        else              { src = S0;  dst = HO_S0;  kt = ((bi-56)>>2); nt = (bi-56)&3; Kvalid = NF;  Kd = 64;  }
        const int flag = detect_bf16(src);
        __shared__ float tile[32][33];
        const int tx = t & 31, ty = t >> 5;
#pragma unroll
        for (int r = 0; r < 4; r++) {
            int k = kt*32 + ty + r*8;
            int n = nt*32 + tx;
            tile[ty + r*8][tx] = (k < Kvalid) ? ldv(src, (long)k*128 + n, flag) : 0.f;
        }
        __syncthreads();
#pragma unroll
        for (int r = 0; r < 4; r++) {
            int n = nt*32 + ty + r*8;
            int k = kt*32 + tx;
            H[dst + n*Kd + k] = (f16)tile[tx][ty + r*8];
        }
    } else {
        if (t == 0) ((int*)F)[FO_FLG] = detect_bf16(x);
        if (t < 128) {
            int c = t;
            {
                float g = ldv(g0,c,detect_bf16(g0)), be = ldv(be0,c,detect_bf16(be0));
                float m = ldv(m0,c,detect_bf16(m0)), v = ldv(v0,c,detect_bf16(v0));
                float b = ldv(b0,c,detect_bf16(b0));
                float A = g * rsqrtf(v + 1e-5f);
                F[FO_A0 + 0*256 + c] = A; F[FO_A0 + 0*256 + 128 + c] = (b - m)*A + be;
            }
            {
                float g = ldv(g1,c,detect_bf16(g1)), be = ldv(be1,c,detect_bf16(be1));
                float m = ldv(m1,c,detect_bf16(m1)), v = ldv(v1,c,detect_bf16(v1));
                float b = ldv(b1,c,detect_bf16(b1));
                float A = g * rsqrtf(v + 1e-5f);
                F[FO_A0 + 1*256 + c] = A; F[FO_A0 + 1*256 + 128 + c] = (b - m)*A + be;
            }
            {
                float g = ldv(g2,c,detect_bf16(g2)), be = ldv(be2,c,detect_bf16(be2));
                float m = ldv(m2,c,detect_bf16(m2)), v = ldv(v2,c,detect_bf16(v2));
                float b = ldv(b2,c,detect_bf16(b2));
                float A = g * rsqrtf(v + 1e-5f);
                F[FO_A0 + 2*256 + c] = A; F[FO_A0 + 2*256 + 128 + c] = (b - m)*A + be;
            }
            F[FO_SB0 + c] = ldv(sb0, c, detect_bf16(sb0));
            F[FO_TB1 + c] = ldv(tb1, c, detect_bf16(tb1));
            F[FO_TW2 + c] = ldv(tW2, c, detect_bf16(tW2));
        }
        const int fA = detect_bf16(adj);
        for (int i = t; i < 1024; i += 256) {
            int r = i >> 5, c = i & 31;
            float v = (r < 25 && c < 25) ? ldv(adj, (long)r*NJ + c, fA) : 0.f;
            H[HO_ADJ32 + i] = (f16)v;
        }
    }
}

// ==== W-body macros (single channel per wave) ====
#define ADJEPI_W(L, WRHB) {                                                     \
    f32x4 zac[2][2];                                                            \
    _Pragma("unroll")                                                           \
    for (int fF = 0; fF < 2; fF++) {                                            \
        half8 bz = *(const half8*)(Pt + (fF*128 + c)*PSTR + q*8);               \
        zac[fF][0] = MFMA16(afadj0, bz, z4);                                    \
        zac[fF][1] = MFMA16(afadj1, bz, z4);                                    \
    }                                                                           \
    const float Av = rA[L], Dv = rD[L];                                         \
    _Pragma("unroll")                                                           \
    for (int fF = 0; fF < 2; fF++) {                                            \
        _Pragma("unroll")                                                       \
        for (int m2 = 0; m2 < 2; m2++) {                                        \
            _Pragma("unroll")                                                   \
            for (int r4 = 0; r4 < 4; r4++) {                                    \
                float zv = (m2 == 0) ? zac[fF][0][r4]                           \
                         : (jlt[r4] ? zac[fF][1][r4] : acc[2*fF+1][r4]);        \
                float hnew = gelu_c(fmaf(zv, Av, Dv)) + hz[fF][m2][r4];         \
                hz[fF][m2][r4] = hnew;                                          \
                if (WRHB)                                                       \
                    hb[((2*fF+m2)*16 + q*4 + r4)*HSTR + c] = (f16)hnew;         \
            }                                                                   \
        }                                                                       \
        {                                                                       \
            float hnew = gelu_c(fmaf(acc[4][fF], Av, Dv)) + h32[fF];            \
            h32[fF] = (q == 0) ? hnew : 0.f;                                    \
            if (WRHB && q == 0)                                                 \
                hb[(64 + fF)*HSTR + c] = (f16)hnew;                             \
        }                                                                       \
    }                                                                           \
}

#define PTWRITE_W(ACC)                                                          \
    _Pragma("unroll")                                                           \
    for (int mt = 0; mt < 4; mt++) {                                            \
        const int fF = mt >> 1;                                                 \
        const int jb = (mt & 1) * 16;                                           \
        f16* pp = Pt + (fF*128 + c)*PSTR;                                       \
        _Pragma("unroll")                                                       \
        for (int r2 = 0; r2 < 4; r2 += 2) {                                     \
            int j0 = jb + q*4 + r2;                                             \
            if (j0 + 1 < 25) {                                                  \
                h2 v2w = { (f16)ACC[mt][r2], (f16)ACC[mt][r2+1] };              \
                *(h2*)(pp + j0) = v2w;                                          \
            } else if (j0 < 25) {                                               \
                pp[j0] = (f16)ACC[mt][r2];                                      \
            }                                                                   \
        }                                                                       \
    }

#define GEMM128_W(WOFF)                                                         \
    {                                                                           \
        half8 bf[4];                                                            \
        _Pragma("unroll")                                                       \
        for (int ks = 0; ks < 4; ks++)                                          \
            bf[ks] = *(const half8*)(HW + (WOFF) + c*128 + ks*32 + q*8);        \
        _Pragma("unroll")                                                       \
        for (int mt = 0; mt < 5; mt++) acc[mt] = z4;                            \
        _Pragma("unroll")                                                       \
        for (int mt = 0; mt < 5; mt++) {                                        \
            const int m = mt*16 + ml;                                           \
            _Pragma("unroll")                                                   \
            for (int ks = 0; ks < 4; ks++) {                                    \
                half8 af = *(const half8*)(hb + m*HSTR + ks*32 + q*8);          \
                acc[mt] = MFMA16(af, bf[ks], acc[mt]);                          \
            }                                                                   \
        }                                                                       \
    }

// ==== W kernel body (everything after LDS declarations) ====
#define GCN_W_BODY                                                              \
    float* xtb = (float*)Pt;                                                    \
    const f16* HW = (const f16*)ws;                                             \
    float* F = (float*)ws;                                                      \
    float* xt_g = F + FO_XT;                                                    \
    float* sc_g = F + FO_SC;                                                    \
    const int t = threadIdx.x, lane = t & 63, wv = t >> 6;                      \
    const int q = lane >> 4, ml = lane & 15;                                    \
    const int c = wv * 16 + ml;                                                 \
    const f32x4 z4 = {0.f, 0.f, 0.f, 0.f};                                      \
    const bool jlt[4] = { q <= 2, q <= 1, q <= 1, q <= 1 };                     \
    const half8 zero8 = {(f16)0.f,(f16)0.f,(f16)0.f,(f16)0.f,(f16)0.f,(f16)0.f,(f16)0.f,(f16)0.f}; \
    {                                                                           \
        int fF = t >> 8, rem = t & 255, n = rem >> 1, chh = rem & 1;            \
        *(half8*)(Pt + (fF*128 + n)*PSTR + 24 + chh*8) = zero8;                 \
    }                                                                           \
    float rA[3], rD[3];                                                         \
    _Pragma("unroll")                                                           \
    for (int L = 0; L < 3; L++) {                                               \
        rA[L] = F[FO_A0 + L*256 + c];                                           \
        rD[L] = F[FO_A0 + L*256 + 128 + c];                                     \
    }                                                                           \
    const float sb0v = F[FO_SB0 + c];                                           \
    half8 afadj0 = *(const half8*)(HW + HO_ADJ32 + ml*32 + q*8);                \
    half8 afadj1 = *(const half8*)(HW + HO_ADJ32 + (16+ml)*32 + q*8);           \
    __syncthreads();                                                            \
    {                                                                           \
        const int fX = ((const int*)F)[FO_FLG];                                 \
        const long xb = (long)blockIdx.x * (SPB * NJ * NF);                     \
        _Pragma("unroll 1")                                                     \
        for (int it = 0; it < 2; it++) {                                        \
            int g = t + it * 512;                                               \
            if (g < 66 * 8) {                                                   \
                int r = g >> 3, blk = g & 7;                                    \
                int fF = (r >= 33) ? 1 : 0;                                     \
                int j = r - 33 * fF;                                            \
                int fr = (j < 32) ? (fF * 32 + j) : (64 + fF);                  \
                half8 o;                                                        \
                if (!fX) {                                                      \
                    const float* base = (const float*)x + xb + (long)r * NF + blk * 8; \
                    if (blk < 6) {                                              \
                        float4 v0 = *(const float4*)base;                       \
                        float4 v1 = *(const float4*)(base + 4);                 \
                        o[0]=(f16)v0.x; o[1]=(f16)v0.y; o[2]=(f16)v0.z; o[3]=(f16)v0.w; \
                        o[4]=(f16)v1.x; o[5]=(f16)v1.y; o[6]=(f16)v1.z; o[7]=(f16)v1.w; \
                    } else if (blk == 6) {                                      \
                        float4 v0 = *(const float4*)base;                       \
                        o = zero8;                                              \
                        o[0]=(f16)v0.x; o[1]=(f16)v0.y; o[2]=(f16)v0.z; o[3]=(f16)v0.w; \
                    } else o = zero8;                                           \
                } else {                                                        \
                    long rb = xb + (long)r * NF;                                \
                    _Pragma("unroll")                                           \
                    for (int i = 0; i < 8; i++) {                               \
                        int cx = blk * 8 + i;                                   \
                        o[i] = (f16)(cx < NF ? bf2f(((const u16*)x)[rb + cx]) : 0.f); \
                    }                                                           \
                }                                                               \
                *(half8*)(hb + fr * HSTR + blk * 8) = o;                        \
            }                                                                   \
        }                                                                       \
    }                                                                           \
    __syncthreads();                                                            \
    f32x4 acc[5];                                                               \
    float hz[2][2][4];                                                          \
    float h32[2];                                                               \
    {                                                                           \
        half8 bw[2], bs[2];                                                     \
        _Pragma("unroll")                                                       \
        for (int ks = 0; ks < 2; ks++) {                                        \
            bw[ks] = *(const half8*)(HW + HO_W0 + c*64 + ks*32 + q*8);          \
            bs[ks] = *(const half8*)(HW + HO_S0 + c*64 + ks*32 + q*8);          \
        }                                                                       \
        f32x4 acs[5];                                                           \
        _Pragma("unroll")                                                       \
        for (int mt = 0; mt < 5; mt++) { acc[mt] = z4; acs[mt] = z4; }          \
        _Pragma("unroll")                                                       \
        for (int mt = 0; mt < 5; mt++) {                                        \
            const int m = mt*16 + ml;                                           \
            half8 a0 = *(const half8*)(hb + m*HSTR + q*8);                      \
            half8 a1 = *(const half8*)(hb + m*HSTR + 32 + q*8);                 \
            acc[mt] = MFMA16(a0, bw[0], acc[mt]);                               \
            acc[mt] = MFMA16(a1, bw[1], acc[mt]);                               \
            acs[mt] = MFMA16(a0, bs[0], acs[mt]);                               \
            acs[mt] = MFMA16(a1, bs[1], acs[mt]);                               \
        }                                                                       \
        __syncthreads();                                                        \
        PTWRITE_W(acc)                                                          \
        _Pragma("unroll")                                                       \
        for (int fF = 0; fF < 2; fF++)                                          \
            _Pragma("unroll")                                                   \
            for (int m2 = 0; m2 < 2; m2++)                                      \
                _Pragma("unroll")                                               \
                for (int r4 = 0; r4 < 4; r4++)                                  \
                    hz[fF][m2][r4] = acs[2*fF+m2][r4] + sb0v;                   \
        _Pragma("unroll")                                                       \
        for (int fF = 0; fF < 2; fF++)                                          \
            h32[fF] = (q == 0) ? (acs[4][fF] + sb0v) : 0.f;                     \
    }                                                                           \
    ADJEPI_W(0, 1)                                                              \
    __syncthreads();                                                            \
    GEMM128_W(HO_W1)                                                            \
    __syncthreads();                                                            \
    PTWRITE_W(acc)                                                              \
    ADJEPI_W(1, 1)                                                              \
    __syncthreads();                                                            \
    GEMM128_W(HO_W2)                                                            \
    __syncthreads();                                                            \
    PTWRITE_W(acc)                                                              \
    ADJEPI_W(2, 0)                                                              \
    __syncthreads();                                                            \
    _Pragma("unroll")                                                           \
    for (int fF = 0; fF < 2; fF++) {                                            \
        float s = h32[fF];                                                      \
        _Pragma("unroll")                                                       \
        for (int m2 = 0; m2 < 2; m2++)                                          \
            _Pragma("unroll")                                                   \
            for (int r4 = 0; r4 < 4; r4++) s += hz[fF][m2][r4];                 \
        s += __shfl_xor(s, 16, 64);                                             \
        s += __shfl_xor(s, 32, 64);                                             \
        float xtc = s * (1.0f / 33.0f);                                         \
        if (q == 0) {                                                           \
            xtb[fF * 128 + c] = xtc;                                            \
            xt_g[((long)blockIdx.x * SPB + fF) * NH + c] = xtc;                 \
        }                                                                       \
    }                                                                           \
    __syncthreads();                                                            \
    {                                                                           \
        float r = 0.f;                                                          \
        if (t < 256) {                                                          \
            const int fF = t >> 7, ch = t & 127;                                \
            float u = 0.f;                                                      \
            _Pragma("unroll")                                                   \
            for (int kk = 0; kk < 16; kk++) {                                   \
                half8 wv8 = *(const half8*)(HW + HO_TW1 + ch*128 + kk*8);       \
                _Pragma("unroll")                                               \
                for (int i = 0; i < 8; i++)                                     \
                    u = fmaf(xtb[fF*128 + kk*8 + i], (float)wv8[i], u);         \
            }                                                                   \
            r = gelu_c(u + F[FO_TB1 + ch]) * F[FO_TW2 + ch];                    \
        }                                                                       \
        _Pragma("unroll")                                                       \
        for (int off = 32; off > 0; off >>= 1) r += __shfl_xor(r, off, 64);     \
        if (lane == 0 && wv < 4) rbuf4[wv] = r;                                 \
        __syncthreads();                                                        \
        if (t == 0) {                                                           \
            sc_g[blockIdx.x * SPB + 0] = rbuf4[0] + rbuf4[1];                   \
            sc_g[blockIdx.x * SPB + 1] = rbuf4[2] + rbuf4[3];                   \
        }                                                                       \
    }

// ==== variant W: R19-proven (56 VGPR, 42.5KB, 3 blocks/CU, 305us) ====
__global__ __launch_bounds__(512) void gcn_mfma_w(const void* __restrict__ x,
                                                  void* __restrict__ ws)
{
    __shared__ __align__(16) f16 hb[80 * HSTR];
    __shared__ __align__(16) f16 Pt[2 * 128 * PSTR];
    __shared__ float rbuf4[4];
    GCN_W_BODY
}

// ==== variant W73: hb 73 rows (40,352B) + FORCED 8 waves/EU (<=64 VGPR) ====
// Natural pressure 56 < budget 64 -> the bound prevents allocator drift,
// not a squeeze (R10's failure was natural-140-forced-128). Correctness:
// hb written rows 0-65 only; tile-4 reads rows 66-79 feed discarded
// outputs (PTWRITE mt<4; h32 rows 64/65 via q==0); max read offset
// 21,712B < 40,352B block. R12-validated.
__global__ __launch_bounds__(512, 8) void gcn_mfma_w73(const void* __restrict__ x,
                                                       void* __restrict__ ws)
{
    __shared__ __align__(16) f16 hb[73 * HSTR];
    __shared__ __align__(16) f16 Pt[2 * 128 * PSTR];
    __shared__ float rbuf4[4];
    GCN_W_BODY
}

// ---- softmax over T + weighted sum -> out[B,H]; shuffle reductions ----
__global__ __launch_bounds__(256) void attn_pool(
    const int* __restrict__ flg,
    const float* __restrict__ xt_ws, const float* __restrict__ score_ws,
    void* __restrict__ out)
{
    __shared__ float ew[NT];
    __shared__ float red[8];
    __shared__ float pb[256];
    const int t = threadIdx.x, lane = t & 63, wv = t >> 6;
    const int b = blockIdx.x >> 2, qr = blockIdx.x & 3;

    float sv = score_ws[b * NT + t];
    float m = sv;
#pragma unroll
    for (int off = 32; off > 0; off >>= 1) m = fmaxf(m, __shfl_xor(m, off, 64));
    if (lane == 0) red[wv] = m;
    __syncthreads();
    float mx = fmaxf(fmaxf(red[0], red[1]), fmaxf(red[2], red[3]));
    float e = __expf(sv - mx);
    ew[t] = e;
    float d = e;
#pragma unroll
    for (int off = 32; off > 0; off >>= 1) d += __shfl_xor(d, off, 64);
    if (lane == 0) red[4 + wv] = d;
    __syncthreads();
    float den = red[4] + red[5] + red[6] + red[7];

    const int cl = t & 31, ch = t >> 5;
    const int c = qr * 32 + cl;
    float a = 0.f;
#pragma unroll 4
    for (int i = ch * 32; i < ch * 32 + 32; i++)
        a = fmaf(ew[i], xt_ws[((long)b * NT + i) * NH + c], a);
    pb[t] = a;
    __syncthreads();
    if (t < 128) pb[t] += pb[t + 128];
    __syncthreads();
    if (t < 64) pb[t] += pb[t + 64];
    __syncthreads();
    if (t < 32) {
        float r = (pb[t] + pb[t + 32]) / den;
        if (*flg) ((__hip_bfloat16*)out)[b * NH + qr * 32 + t] = __float2bfloat16(r);
        else      ((float*)out)[b * NH + qr * 32 + t] = r;
    }
}

extern "C" void kernel_launch(void* const* d_in, const int* in_sizes, int n_in,
                              void* d_out, int out_size, void* d_ws, size_t ws_size,
                              hipStream_t stream) {
    // Host-side attribute gate (graph-capture-safe): W73 needs <=64 VGPR AND
    // zero scratch (forced bounds can spill — R10 lesson). Fallback = W.
    static int use_73 = -1;
    if (use_73 < 0) {
        hipFuncAttributes a{};
        use_73 = 0;
        if (hipFuncGetAttributes(&a, reinterpret_cast<const void*>(gcn_mfma_w73)) == hipSuccess
            && a.numRegs > 0 && a.numRegs <= 64
            && a.localSizeBytes == 0)
            use_73 = 1;
    }
    prep<<<65, 256, 0, stream>>>(
        d_in[0], d_in[1],
        d_in[2], d_in[3], d_in[4], d_in[5],
        d_in[6], d_in[7], d_in[8], d_in[9],
        d_in[10], d_in[11], d_in[12], d_in[13], d_in[14], d_in[15],
        d_in[16], d_in[17], d_in[18], d_in[19], d_in[20], d_in[21],
        d_in[22], d_in[23], d_in[24],
        d_ws);
    if (use_73) gcn_mfma_w73<<<NBLKS, 512, 0, stream>>>(d_in[0], d_ws);
    else        gcn_mfma_w<<<NBLKS, 512, 0, stream>>>(d_in[0], d_ws);
    float* F = (float*)d_ws;
    attn_pool<<<NB * 4, 256, 0, stream>>>((const int*)(F + FO_FLG), F + FO_XT, F + FO_SC, d_out);
}

// Round 13
// 489.510 us; speedup vs baseline: 1.0352x; 1.0352x over previous
//
#include <hip/hip_runtime.h>
#include <hip/hip_bf16.h>
#include <math.h>

// TemporalSkeletonBranch — Round 22: single-frame Pt (32KB LDS) + occupancy-
// API gate.
// R21 post-mortem: 9th reg-lottery loss on the hb-shrink path (even forced
// launch_bounds spilled/drifted). Two changes: (1) gate via
// hipOccupancyMaxActiveBlocksPerMultiprocessor — authoritative blocks/CU,
// no VGPR-threshold guessing; (2) new LDS cut: Pt is WAVE-PRIVATE on the
// W body and both frames' P live in acc[0..3], so frames can share ONE
// Pt[128][PSTR] buffer (PTWRITE(f0);ADJEPI(f0);PTWRITE(f1);ADJEPI(f1),
// same-wave DS ordering, zero extra barriers). LDS 42,496 -> 32,016 ->
// 4 blocks x 8 waves = 32 waves/CU (vs 24). R11's frame-split failed on
// VGPR (256-thr body, 140 regs); W body is at 56 with halved state.
// Secondary: Wg = W + sigmoid gelu (7 vs 12 ops x ~54 calls). Fallback W.

#define NJ 33
#define NF 52
#define NH 128
#define NT 256
#define NB 64
#define NSAMP (NB*NT)       // 16384
#define SPB 2               // samples per block
#define NBLKS (NSAMP/SPB)   // 8192
#define HSTR 136            // hb row stride (halves)
#define PSTR 40             // Pt k-stride (halves)

typedef unsigned short u16;
typedef _Float16 f16;
typedef f16   half8 __attribute__((ext_vector_type(8)));
typedef f16   h2    __attribute__((ext_vector_type(2)));
typedef float f32x4 __attribute__((ext_vector_type(4)));

// ---- workspace layout ----
#define HO_W0    0            // [n=128][k=64]
#define HO_S0    8192
#define HO_W1    16384        // [n=128][k=128]
#define HO_W2    32768
#define HO_TW1   49152
#define HO_ADJ32 65536        // [32][32] f16, rows/cols 25..31 = 0
#define H_TOTAL  66560
#define FO_BASE  (H_TOTAL/2)  // 33280 floats
#define FO_A0    (FO_BASE+0)  // [L*256 + {A:c, D:128+c}]
#define FO_SB0   (FO_BASE+768)
#define FO_TB1   (FO_BASE+896)
#define FO_TW2   (FO_BASE+1024)
#define FO_FLG   (FO_BASE+1152)   // int: x is bf16?
#define FO_XT    (FO_BASE+1280)
#define FO_SC    (FO_XT + NSAMP*NH)

__device__ __forceinline__ float bf2f(u16 u) { return __uint_as_float(((unsigned)u) << 16); }
__device__ __forceinline__ float ldv(const void* p, long i, int f) {
    float r;
    if (f) r = bf2f(((const u16*)p)[i]);
    else   r = ((const float*)p)[i];
    return r;
}
__device__ int detect_bf16(const void* p) {
    const u16* q = (const u16*)p;
    int nz = 0, ok = 0;
#pragma unroll
    for (int k = 0; k < 64; k++) {
        u16 u = q[k];
        if (u & 0x7FFF) {
            nz++;
            int e = (u >> 7) & 0xFF;
            ok += (e >= 0x40 && e <= 0xBF) ? 1 : 0;
        }
    }
    return (nz == 0) || (ok * 20 >= nz * 19);
}

// clamped tanh-form gelu (R9-proven): exp2+rcp, ~12 VALU ops
__device__ __forceinline__ float gelu_c(float x) {
    float xc = fminf(fmaxf(x, -8.f), 8.f);
    float u  = xc * fmaf(xc * xc, 0.10294324f, 2.3022082f);
#if __has_builtin(__builtin_amdgcn_exp2f)
    float e  = __builtin_amdgcn_exp2f(u);
#else
    float e  = exp2f(u);
#endif
#if __has_builtin(__builtin_amdgcn_rcpf)
    float tt = (e - 1.f) * __builtin_amdgcn_rcpf(e + 1.f);
#else
    float tt = (e - 1.f) / (e + 1.f);
#endif
    float hx = 0.5f * x;
    return fmaf(hx, tt, hx);
}

// sigmoid-form of the same approximation: x*rcp(1+2^-u), ~7 ops, clampless
// (rcp saturates: x->-inf gives 0, x->+inf gives x). R10/R11-proven numerics.
__device__ __forceinline__ float gelu_s(float x) {
    float nu = x * fmaf(x * x, -0.10294324f, -2.3022082f);
#if __has_builtin(__builtin_amdgcn_exp2f)
    float e  = __builtin_amdgcn_exp2f(nu);
#else
    float e  = exp2f(nu);
#endif
#if __has_builtin(__builtin_amdgcn_rcpf)
    return x * __builtin_amdgcn_rcpf(1.f + e);
#else
    return x / (1.f + e);
#endif
}

#define MFMA16(a, b, c) __builtin_amdgcn_mfma_f32_16x16x32_f16(a, b, c, 0, 0, 0)

// ---- prep: 65-block tiled transpose + folded BN + adj32 + dtype flags ----
__global__ __launch_bounds__(256) void prep(
    const void* x, const void* adj,
    const void* W0, const void* b0, const void* S0, const void* sb0,
    const void* g0, const void* be0, const void* m0, const void* v0,
    const void* W1, const void* b1, const void* g1, const void* be1, const void* m1, const void* v1,
    const void* W2, const void* b2, const void* g2, const void* be2, const void* m2, const void* v2,
    const void* tW1, const void* tb1, const void* tW2,
    void* ws)
{
    f16* H = (f16*)ws; float* F = (float*)ws;
    const int bi = blockIdx.x, t = threadIdx.x;

    if (bi < 64) {
        const void* src; int dst, kt, nt, Kvalid, Kd;
        if (bi < 16)      { src = W1;  dst = HO_W1;  kt = (bi>>2)&3;    nt = bi&3;      Kvalid = 128; Kd = 128; }
        else if (bi < 32) { src = W2;  dst = HO_W2;  kt = ((bi-16)>>2); nt = (bi-16)&3; Kvalid = 128; Kd = 128; }
        else if (bi < 48) { src = tW1; dst = HO_TW1; kt = ((bi-32)>>2); nt = (bi-32)&3; Kvalid = 128; Kd = 128; }
        else if (bi < 56) { src = W0;  dst = HO_W0;  kt = ((bi-48)>>2); nt = (bi-48)&3; Kvalid = NF;  Kd = 64;  }
        else              { src = S0;  dst = HO_S0;  kt = ((bi-56)>>2); nt = (bi-56)&3; Kvalid = NF;  Kd = 64;  }
        const int flag = detect_bf16(src);
        __shared__ float tile[32][33];
        const int tx = t & 31, ty = t >> 5;
#pragma unroll
        for (int r = 0; r < 4; r++) {
            int k = kt*32 + ty + r*8;
            int n = nt*32 + tx;
            tile[ty + r*8][tx] = (k < Kvalid) ? ldv(src, (long)k*128 + n, flag) : 0.f;
        }
        __syncthreads();
#pragma unroll
        for (int r = 0; r < 4; r++) {
            int n = nt*32 + ty + r*8;
            int k = kt*32 + tx;
            H[dst + n*Kd + k] = (f16)tile[tx][ty + r*8];
        }
    } else {
        if (t == 0) ((int*)F)[FO_FLG] = detect_bf16(x);
        if (t < 128) {
            int c = t;
            {
                float g = ldv(g0,c,detect_bf16(g0)), be = ldv(be0,c,detect_bf16(be0));
                float m = ldv(m0,c,detect_bf16(m0)), v = ldv(v0,c,detect_bf16(v0));
                float b = ldv(b0,c,detect_bf16(b0));
                float A = g * rsqrtf(v + 1e-5f);
                F[FO_A0 + 0*256 + c] = A; F[FO_A0 + 0*256 + 128 + c] = (b - m)*A + be;
            }
            {
                float g = ldv(g1,c,detect_bf16(g1)), be = ldv(be1,c,detect_bf16(be1));
                float m = ldv(m1,c,detect_bf16(m1)), v = ldv(v1,c,detect_bf16(v1));
                float b = ldv(b1,c,detect_bf16(b1));
                float A = g * rsqrtf(v + 1e-5f);
                F[FO_A0 + 1*256 + c] = A; F[FO_A0 + 1*256 + 128 + c] = (b - m)*A + be;
            }
            {
                float g = ldv(g2,c,detect_bf16(g2)), be = ldv(be2,c,detect_bf16(be2));
                float m = ldv(m2,c,detect_bf16(m2)), v = ldv(v2,c,detect_bf16(v2));
                float b = ldv(b2,c,detect_bf16(b2));
                float A = g * rsqrtf(v + 1e-5f);
                F[FO_A0 + 2*256 + c] = A; F[FO_A0 + 2*256 + 128 + c] = (b - m)*A + be;
            }
            F[FO_SB0 + c] = ldv(sb0, c, detect_bf16(sb0));
            F[FO_TB1 + c] = ldv(tb1, c, detect_bf16(tb1));
            F[FO_TW2 + c] = ldv(tW2, c, detect_bf16(tW2));
        }
        const int fA = detect_bf16(adj);
        for (int i = t; i < 1024; i += 256) {
            int r = i >> 5, c = i & 31;
            float v = (r < 25 && c < 25) ? ldv(adj, (long)r*NJ + c, fA) : 0.f;
            H[HO_ADJ32 + i] = (f16)v;
        }
    }
}

// ==== shared: x -> hb staging (512 threads) ====
#define STAGE_X                                                                 \
    {                                                                           \
        const int fX = ((const int*)F)[FO_FLG];                                 \
        const long xb = (long)blockIdx.x * (SPB * NJ * NF);                     \
        _Pragma("unroll 1")                                                     \
        for (int it = 0; it < 2; it++) {                                        \
            int g = t + it * 512;                                               \
            if (g < 66 * 8) {                                                   \
                int r = g >> 3, blk = g & 7;                                    \
                int fF = (r >= 33) ? 1 : 0;                                     \
                int j = r - 33 * fF;                                            \
                int fr = (j < 32) ? (fF * 32 + j) : (64 + fF);                  \
                half8 o;                                                        \
                if (!fX) {                                                      \
                    const float* base = (const float*)x + xb + (long)r * NF + blk * 8; \
                    if (blk < 6) {                                              \
                        float4 v0 = *(const float4*)base;                       \
                        float4 v1 = *(const float4*)(base + 4);                 \
                        o[0]=(f16)v0.x; o[1]=(f16)v0.y; o[2]=(f16)v0.z; o[3]=(f16)v0.w; \
                        o[4]=(f16)v1.x; o[5]=(f16)v1.y; o[6]=(f16)v1.z; o[7]=(f16)v1.w; \
                    } else if (blk == 6) {                                      \
                        float4 v0 = *(const float4*)base;                       \
                        o = zero8;                                              \
                        o[0]=(f16)v0.x; o[1]=(f16)v0.y; o[2]=(f16)v0.z; o[3]=(f16)v0.w; \
                    } else o = zero8;                                           \
                } else {                                                        \
                    long rb = xb + (long)r * NF;                                \
                    _Pragma("unroll")                                           \
                    for (int i = 0; i < 8; i++) {                               \
                        int cx = blk * 8 + i;                                   \
                        o[i] = (f16)(cx < NF ? bf2f(((const u16*)x)[rb + cx]) : 0.f); \
                    }                                                           \
                }                                                               \
                *(half8*)(hb + fr * HSTR + blk * 8) = o;                        \
            }                                                                   \
        }                                                                       \
    }

#define GEMM128_W(WOFF)                                                         \
    {                                                                           \
        half8 bf[4];                                                            \
        _Pragma("unroll")                                                       \
        for (int ks = 0; ks < 4; ks++)                                          \
            bf[ks] = *(const half8*)(HW + (WOFF) + c*128 + ks*32 + q*8);        \
        _Pragma("unroll")                                                       \
        for (int mt = 0; mt < 5; mt++) acc[mt] = z4;                            \
        _Pragma("unroll")                                                       \
        for (int mt = 0; mt < 5; mt++) {                                        \
            const int m = mt*16 + ml;                                           \
            _Pragma("unroll")                                                   \
            for (int ks = 0; ks < 4; ks++) {                                    \
                half8 af = *(const half8*)(hb + m*HSTR + ks*32 + q*8);          \
                acc[mt] = MFMA16(af, bf[ks], acc[mt]);                          \
            }                                                                   \
        }                                                                       \
    }

// ==== shared: mean + score MLP tail ====
#define TAIL_W(GELUF)                                                           \
    _Pragma("unroll")                                                           \
    for (int fF = 0; fF < 2; fF++) {                                            \
        float s = h32[fF];                                                      \
        _Pragma("unroll")                                                       \
        for (int m2 = 0; m2 < 2; m2++)                                          \
            _Pragma("unroll")                                                   \
            for (int r4 = 0; r4 < 4; r4++) s += hz[fF][m2][r4];                 \
        s += __shfl_xor(s, 16, 64);                                             \
        s += __shfl_xor(s, 32, 64);                                             \
        float xtc = s * (1.0f / 33.0f);                                         \
        if (q == 0) {                                                           \
            xtb[fF * 128 + c] = xtc;                                            \
            xt_g[((long)blockIdx.x * SPB + fF) * NH + c] = xtc;                 \
        }                                                                       \
    }                                                                           \
    __syncthreads();                                                            \
    {                                                                           \
        float r = 0.f;                                                          \
        if (t < 256) {                                                          \
            const int fF = t >> 7, ch = t & 127;                                \
            float u = 0.f;                                                      \
            _Pragma("unroll")                                                   \
            for (int kk = 0; kk < 16; kk++) {                                   \
                half8 wv8 = *(const half8*)(HW + HO_TW1 + ch*128 + kk*8);       \
                _Pragma("unroll")                                               \
                for (int i = 0; i < 8; i++)                                     \
                    u = fmaf(xtb[fF*128 + kk*8 + i], (float)wv8[i], u);         \
            }                                                                   \
            r = GELUF(u + F[FO_TB1 + ch]) * F[FO_TW2 + ch];                     \
        }                                                                       \
        _Pragma("unroll")                                                       \
        for (int off = 32; off > 0; off >>= 1) r += __shfl_xor(r, off, 64);     \
        if (lane == 0 && wv < 4) rbuf4[wv] = r;                                 \
        __syncthreads();                                                        \
        if (t == 0) {                                                           \
            sc_g[blockIdx.x * SPB + 0] = rbuf4[0] + rbuf4[1];                   \
            sc_g[blockIdx.x * SPB + 1] = rbuf4[2] + rbuf4[3];                   \
        }                                                                       \
    }

// ==== dual-frame-Pt macros (variants W / Wg) ====
#define ADJEPI_W(L, WRHB, GELUF) {                                              \
    f32x4 zac[2][2];                                                            \
    _Pragma("unroll")                                                           \
    for (int fF = 0; fF < 2; fF++) {                                            \
        half8 bz = *(const half8*)(Pt + (fF*128 + c)*PSTR + q*8);               \
        zac[fF][0] = MFMA16(afadj0, bz, z4);                                    \
        zac[fF][1] = MFMA16(afadj1, bz, z4);                                    \
    }                                                                           \
    const float Av = rA[L], Dv = rD[L];                                         \
    _Pragma("unroll")                                                           \
    for (int fF = 0; fF < 2; fF++) {                                            \
        _Pragma("unroll")                                                       \
        for (int m2 = 0; m2 < 2; m2++) {                                        \
            _Pragma("unroll")                                                   \
            for (int r4 = 0; r4 < 4; r4++) {                                    \
                float zv = (m2 == 0) ? zac[fF][0][r4]                           \
                         : (jlt[r4] ? zac[fF][1][r4] : acc[2*fF+1][r4]);        \
                float hnew = GELUF(fmaf(zv, Av, Dv)) + hz[fF][m2][r4];          \
                hz[fF][m2][r4] = hnew;                                          \
                if (WRHB)                                                       \
                    hb[((2*fF+m2)*16 + q*4 + r4)*HSTR + c] = (f16)hnew;         \
            }                                                                   \
        }                                                                       \
        {                                                                       \
            float hnew = GELUF(fmaf(acc[4][fF], Av, Dv)) + h32[fF];             \
            h32[fF] = (q == 0) ? hnew : 0.f;                                    \
            if (WRHB && q == 0)                                                 \
                hb[(64 + fF)*HSTR + c] = (f16)hnew;                             \
        }                                                                       \
    }                                                                           \
}

#define PTWRITE_W(ACC)                                                          \
    _Pragma("unroll")                                                           \
    for (int mt = 0; mt < 4; mt++) {                                            \
        const int fF = mt >> 1;                                                 \
        const int jb = (mt & 1) * 16;                                           \
        f16* pp = Pt + (fF*128 + c)*PSTR;                                       \
        _Pragma("unroll")                                                       \
        for (int r2 = 0; r2 < 4; r2 += 2) {                                     \
            int j0 = jb + q*4 + r2;                                             \
            if (j0 + 1 < 25) {                                                  \
                h2 v2w = { (f16)ACC[mt][r2], (f16)ACC[mt][r2+1] };              \
                *(h2*)(pp + j0) = v2w;                                          \
            } else if (j0 < 25) {                                               \
                pp[j0] = (f16)ACC[mt][r2];                                      \
            }                                                                   \
        }                                                                       \
    }

#define GCN_W_BODY(GELUF)                                                       \
    float* xtb = (float*)Pt;                                                    \
    const f16* HW = (const f16*)ws;                                             \
    float* F = (float*)ws;                                                      \
    float* xt_g = F + FO_XT;                                                    \
    float* sc_g = F + FO_SC;                                                    \
    const int t = threadIdx.x, lane = t & 63, wv = t >> 6;                      \
    const int q = lane >> 4, ml = lane & 15;                                    \
    const int c = wv * 16 + ml;                                                 \
    const f32x4 z4 = {0.f, 0.f, 0.f, 0.f};                                      \
    const bool jlt[4] = { q <= 2, q <= 1, q <= 1, q <= 1 };                     \
    const half8 zero8 = {(f16)0.f,(f16)0.f,(f16)0.f,(f16)0.f,(f16)0.f,(f16)0.f,(f16)0.f,(f16)0.f}; \
    {                                                                           \
        int fF = t >> 8, rem = t & 255, n = rem >> 1, chh = rem & 1;            \
        *(half8*)(Pt + (fF*128 + n)*PSTR + 24 + chh*8) = zero8;                 \
    }                                                                           \
    float rA[3], rD[3];                                                         \
    _Pragma("unroll")                                                           \
    for (int L = 0; L < 3; L++) {                                               \
        rA[L] = F[FO_A0 + L*256 + c];                                           \
        rD[L] = F[FO_A0 + L*256 + 128 + c];                                     \
    }                                                                           \
    const float sb0v = F[FO_SB0 + c];                                           \
    half8 afadj0 = *(const half8*)(HW + HO_ADJ32 + ml*32 + q*8);                \
    half8 afadj1 = *(const half8*)(HW + HO_ADJ32 + (16+ml)*32 + q*8);           \
    __syncthreads();                                                            \
    STAGE_X                                                                     \
    __syncthreads();                                                            \
    f32x4 acc[5];                                                               \
    float hz[2][2][4];                                                          \
    float h32[2];                                                               \
    {                                                                           \
        half8 bw[2], bs[2];                                                     \
        _Pragma("unroll")                                                       \
        for (int ks = 0; ks < 2; ks++) {                                        \
            bw[ks] = *(const half8*)(HW + HO_W0 + c*64 + ks*32 + q*8);          \
            bs[ks] = *(const half8*)(HW + HO_S0 + c*64 + ks*32 + q*8);          \
        }                                                                       \
        f32x4 acs[5];                                                           \
        _Pragma("unroll")                                                       \
        for (int mt = 0; mt < 5; mt++) { acc[mt] = z4; acs[mt] = z4; }          \
        _Pragma("unroll")                                                       \
        for (int mt = 0; mt < 5; mt++) {                                        \
            const int m = mt*16 + ml;                                           \
            half8 a0 = *(const half8*)(hb + m*HSTR + q*8);                      \
            half8 a1 = *(const half8*)(hb + m*HSTR + 32 + q*8);                 \
            acc[mt] = MFMA16(a0, bw[0], acc[mt]);                               \
            acc[mt] = MFMA16(a1, bw[1], acc[mt]);                               \
            acs[mt] = MFMA16(a0, bs[0], acs[mt]);                               \
            acs[mt] = MFMA16(a1, bs[1], acs[mt]);                               \
        }                                                                       \
        __syncthreads();                                                        \
        PTWRITE_W(acc)                                                          \
        _Pragma("unroll")                                                       \
        for (int fF = 0; fF < 2; fF++)                                          \
            _Pragma("unroll")                                                   \
            for (int m2 = 0; m2 < 2; m2++)                                      \
                _Pragma("unroll")                                               \
                for (int r4 = 0; r4 < 4; r4++)                                  \
                    hz[fF][m2][r4] = acs[2*fF+m2][r4] + sb0v;                   \
        _Pragma("unroll")                                                       \
        for (int fF = 0; fF < 2; fF++)                                          \
            h32[fF] = (q == 0) ? (acs[4][fF] + sb0v) : 0.f;                     \
    }                                                                           \
    ADJEPI_W(0, 1, GELUF)                                                       \
    __syncthreads();                                                            \
    GEMM128_W(HO_W1)                                                            \
    __syncthreads();                                                            \
    PTWRITE_W(acc)                                                              \
    ADJEPI_W(1, 1, GELUF)                                                       \
    __syncthreads();                                                            \
    GEMM128_W(HO_W2)                                                            \
    __syncthreads();                                                            \
    PTWRITE_W(acc)                                                              \
    ADJEPI_W(2, 0, GELUF)                                                       \
    __syncthreads();                                                            \
    TAIL_W(GELUF)

// ==== single-frame-Pt macros (variant WPt) ====
#define ADJEPI_WF(L, FF, WRHB) {                                                \
    half8 bz = *(const half8*)(Pt + c*PSTR + q*8);                              \
    f32x4 zac0 = MFMA16(afadj0, bz, z4);                                        \
    f32x4 zac1 = MFMA16(afadj1, bz, z4);                                        \
    const float Av = rA[L], Dv = rD[L];                                         \
    _Pragma("unroll")                                                           \
    for (int m2 = 0; m2 < 2; m2++) {                                            \
        _Pragma("unroll")                                                       \
        for (int r4 = 0; r4 < 4; r4++) {                                        \
            float zv = (m2 == 0) ? zac0[r4]                                     \
                     : (jlt[r4] ? zac1[r4] : acc[2*(FF)+1][r4]);                \
            float hnew = gelu_c(fmaf(zv, Av, Dv)) + hz[FF][m2][r4];             \
            hz[FF][m2][r4] = hnew;                                              \
            if (WRHB)                                                           \
                hb[((2*(FF)+m2)*16 + q*4 + r4)*HSTR + c] = (f16)hnew;           \
        }                                                                       \
    }                                                                           \
    {                                                                           \
        float hnew = gelu_c(fmaf(acc[4][FF], Av, Dv)) + h32[FF];                \
        h32[FF] = (q == 0) ? hnew : 0.f;                                        \
        if (WRHB && q == 0)                                                     \
            hb[(64 + (FF))*HSTR + c] = (f16)hnew;                               \
    }                                                                           \
}

#define PTWRITE_WF(ACC, FF)                                                     \
    _Pragma("unroll")                                                           \
    for (int mtl = 0; mtl < 2; mtl++) {                                         \
        const int mt = 2*(FF) + mtl;                                            \
        const int jb = mtl * 16;                                                \
        f16* pp = Pt + c*PSTR;                                                  \
        _Pragma("unroll")                                                       \
        for (int r2 = 0; r2 < 4; r2 += 2) {                                     \
            int j0 = jb + q*4 + r2;                                             \
            if (j0 + 1 < 25) {                                                  \
                h2 v2w = { (f16)ACC[mt][r2], (f16)ACC[mt][r2+1] };              \
                *(h2*)(pp + j0) = v2w;                                          \
            } else if (j0 < 25) {                                               \
                pp[j0] = (f16)ACC[mt][r2];                                      \
            }                                                                   \
        }                                                                       \
    }

// ==== variant W: R19-proven (56 VGPR, 42.5KB, 3 blocks/CU, ~304us) ====
__global__ __launch_bounds__(512) void gcn_mfma_w(const void* __restrict__ x,
                                                  void* __restrict__ ws)
{
    __shared__ __align__(16) f16 hb[80 * HSTR];
    __shared__ __align__(16) f16 Pt[2 * 128 * PSTR];
    __shared__ float rbuf4[4];
    GCN_W_BODY(gelu_c)
}

// ==== variant Wg: W + sigmoid gelu (VALU cut only) ====
__global__ __launch_bounds__(512) void gcn_mfma_wg(const void* __restrict__ x,
                                                   void* __restrict__ ws)
{
    __shared__ __align__(16) f16 hb[80 * HSTR];
    __shared__ __align__(16) f16 Pt[2 * 128 * PSTR];
    __shared__ float rbuf4[4];
    GCN_W_BODY(gelu_s)
}

// ==== variant WPt: single-frame Pt — LDS 32,016B -> 4 blocks x 8 waves ====
// Pt is wave-private (each wave touches only channel c) and both frames'
// P live in acc[0..3], so frames share one buffer: PTWRITE(f0);ADJEPI(f0);
// PTWRITE(f1);ADJEPI(f1). Same-wave DS ordering covers the RAW; barrier
// structure unchanged (barriers only protect cross-wave hb access).
__global__ __launch_bounds__(512) void gcn_mfma_wpt(const void* __restrict__ x,
                                                    void* __restrict__ ws)
{
    __shared__ __align__(16) f16 hb[80 * HSTR];     // 21,760 B
    __shared__ __align__(16) f16 Pt[128 * PSTR];    // 10,240 B
    __shared__ float rbuf4[4];
    float* xtb = (float*)Pt;
    const f16* HW = (const f16*)ws;
    float* F = (float*)ws;
    float* xt_g = F + FO_XT;
    float* sc_g = F + FO_SC;
    const int t = threadIdx.x, lane = t & 63, wv = t >> 6;
    const int q = lane >> 4, ml = lane & 15;
    const int c = wv * 16 + ml;
    const f32x4 z4 = {0.f, 0.f, 0.f, 0.f};
    const bool jlt[4] = { q <= 2, q <= 1, q <= 1, q <= 1 };
    const half8 zero8 = {(f16)0.f,(f16)0.f,(f16)0.f,(f16)0.f,(f16)0.f,(f16)0.f,(f16)0.f,(f16)0.f};
    // zero Pt k=24..39 for all 128 channels (256 items over first 256 threads)
    if (t < 256) {
        int n = t >> 1, chh = t & 1;
        *(half8*)(Pt + n*PSTR + 24 + chh*8) = zero8;
    }
    float rA[3], rD[3];
#pragma unroll
    for (int L = 0; L < 3; L++) {
        rA[L] = F[FO_A0 + L*256 + c];
        rD[L] = F[FO_A0 + L*256 + 128 + c];
    }
    const float sb0v = F[FO_SB0 + c];
    half8 afadj0 = *(const half8*)(HW + HO_ADJ32 + ml*32 + q*8);
    half8 afadj1 = *(const half8*)(HW + HO_ADJ32 + (16+ml)*32 + q*8);
    __syncthreads();
    STAGE_X
    __syncthreads();
    f32x4 acc[5];
    float hz[2][2][4];
    float h32[2];
    {
        half8 bw[2], bs[2];
#pragma unroll
        for (int ks = 0; ks < 2; ks++) {
            bw[ks] = *(const half8*)(HW + HO_W0 + c*64 + ks*32 + q*8);
            bs[ks] = *(const half8*)(HW + HO_S0 + c*64 + ks*32 + q*8);
        }
        f32x4 acs[5];
#pragma unroll
        for (int mt = 0; mt < 5; mt++) { acc[mt] = z4; acs[mt] = z4; }
#pragma unroll
        for (int mt = 0; mt < 5; mt++) {
            const int m = mt*16 + ml;
            half8 a0 = *(const half8*)(hb + m*HSTR + q*8);
            half8 a1 = *(const half8*)(hb + m*HSTR + 32 + q*8);
            acc[mt] = MFMA16(a0, bw[0], acc[mt]);
            acc[mt] = MFMA16(a1, bw[1], acc[mt]);
            acs[mt] = MFMA16(a0, bs[0], acs[mt]);
            acs[mt] = MFMA16(a1, bs[1], acs[mt]);
        }
        __syncthreads();               // x reads done before hb writes below
#pragma unroll
        for (int fF = 0; fF < 2; fF++)
#pragma unroll
            for (int m2 = 0; m2 < 2; m2++)
#pragma unroll
                for (int r4 = 0; r4 < 4; r4++)
                    hz[fF][m2][r4] = acs[2*fF+m2][r4] + sb0v;
#pragma unroll
        for (int fF = 0; fF < 2; fF++)
            h32[fF] = (q == 0) ? (acs[4][fF] + sb0v) : 0.f;
    }
    PTWRITE_WF(acc, 0)
    ADJEPI_WF(0, 0, 1)
    PTWRITE_WF(acc, 1)
    ADJEPI_WF(0, 1, 1)
    __syncthreads();
    GEMM128_W(HO_W1)
    __syncthreads();
    PTWRITE_WF(acc, 0)
    ADJEPI_WF(1, 0, 1)
    PTWRITE_WF(acc, 1)
    ADJEPI_WF(1, 1, 1)
    __syncthreads();
    GEMM128_W(HO_W2)
    __syncthreads();
    PTWRITE_WF(acc, 0)
    ADJEPI_WF(2, 0, 0)
    PTWRITE_WF(acc, 1)
    ADJEPI_WF(2, 1, 0)
    __syncthreads();                   // Pt reads done before xtb alias writes
    TAIL_W(gelu_c)
}

// ---- softmax over T + weighted sum -> out[B,H]; shuffle reductions ----
__global__ __launch_bounds__(256) void attn_pool(
    const int* __restrict__ flg,
    const float* __restrict__ xt_ws, const float* __restrict__ score_ws,
    void* __restrict__ out)
{
    __shared__ float ew[NT];
    __shared__ float red[8];
    __shared__ float pb[256];
    const int t = threadIdx.x, lane = t & 63, wv = t >> 6;
    const int b = blockIdx.x >> 2, qr = blockIdx.x & 3;

    float sv = score_ws[b * NT + t];
    float m = sv;
#pragma unroll
    for (int off = 32; off > 0; off >>= 1) m = fmaxf(m, __shfl_xor(m, off, 64));
    if (lane == 0) red[wv] = m;
    __syncthreads();
    float mx = fmaxf(fmaxf(red[0], red[1]), fmaxf(red[2], red[3]));
    float e = __expf(sv - mx);
    ew[t] = e;
    float d = e;
#pragma unroll
    for (int off = 32; off > 0; off >>= 1) d += __shfl_xor(d, off, 64);
    if (lane == 0) red[4 + wv] = d;
    __syncthreads();
    float den = red[4] + red[5] + red[6] + red[7];

    const int cl = t & 31, ch = t >> 5;
    const int c = qr * 32 + cl;
    float a = 0.f;
#pragma unroll 4
    for (int i = ch * 32; i < ch * 32 + 32; i++)
        a = fmaf(ew[i], xt_ws[((long)b * NT + i) * NH + c], a);
    pb[t] = a;
    __syncthreads();
    if (t < 128) pb[t] += pb[t + 128];
    __syncthreads();
    if (t < 64) pb[t] += pb[t + 64];
    __syncthreads();
    if (t < 32) {
        float r = (pb[t] + pb[t + 32]) / den;
        if (*flg) ((__hip_bfloat16*)out)[b * NH + qr * 32 + t] = __float2bfloat16(r);
        else      ((float*)out)[b * NH + qr * 32 + t] = r;
    }
}

extern "C" void kernel_launch(void* const* d_in, const int* in_sizes, int n_in,
                              void* d_out, int out_size, void* d_ws, size_t ws_size,
                              hipStream_t stream) {
    // Host-side gate (graph-capture-safe) using the AUTHORITATIVE occupancy
    // API (folds VGPR steps + LDS + wave slots) + zero-scratch check.
    static int pick = -1;
    if (pick < 0) {
        auto occ = [](const void* f) -> int {
            int n = 0;
            return (hipOccupancyMaxActiveBlocksPerMultiprocessor(&n, f, 512, 0)
                    == hipSuccess) ? n : 0;
        };
        auto clean = [](const void* f) -> bool {
            hipFuncAttributes a{};
            return hipFuncGetAttributes(&a, f) == hipSuccess
                   && a.localSizeBytes == 0;
        };
        const void* fw   = reinterpret_cast<const void*>(gcn_mfma_w);
        const void* fwpt = reinterpret_cast<const void*>(gcn_mfma_wpt);
        const void* fwg  = reinterpret_cast<const void*>(gcn_mfma_wg);
        int ow = occ(fw);
        pick = 2;                                           // fallback W
        if (clean(fwpt) && occ(fwpt) > ow)      pick = 0;   // 4 blocks/CU
        else if (clean(fwg) && occ(fwg) >= ow)  pick = 1;   // VALU cut
    }
    prep<<<65, 256, 0, stream>>>(
        d_in[0], d_in[1],
        d_in[2], d_in[3], d_in[4], d_in[5],
        d_in[6], d_in[7], d_in[8], d_in[9],
        d_in[10], d_in[11], d_in[12], d_in[13], d_in[14], d_in[15],
        d_in[16], d_in[17], d_in[18], d_in[19], d_in[20], d_in[21],
        d_in[22], d_in[23], d_in[24],
        d_ws);
    if      (pick == 0) gcn_mfma_wpt<<<NBLKS, 512, 0, stream>>>(d_in[0], d_ws);
    else if (pick == 1) gcn_mfma_wg <<<NBLKS, 512, 0, stream>>>(d_in[0], d_ws);
    else                gcn_mfma_w  <<<NBLKS, 512, 0, stream>>>(d_in[0], d_ws);
    float* F = (float*)d_ws;
    attn_pool<<<NB * 4, 256, 0, stream>>>((const int*)(F + FO_FLG), F + FO_XT, F + FO_SC, d_out);
}